// Round 8
// baseline (536.984 us; speedup 1.0000x reference)
//
#include <hip/hip_runtime.h>
#include <hip/hip_bf16.h>

typedef __attribute__((ext_vector_type(8))) __bf16 bf16x8;
typedef __attribute__((ext_vector_type(4))) __bf16 bf16x4;
typedef __attribute__((ext_vector_type(4))) float f32x4;

#define LOG2E 1.4426950408889634f
#define FIXED_M 16.0f

static __device__ __forceinline__ f32x4 mfma16(bf16x8 a, bf16x8 b, f32x4 c) {
  return __builtin_amdgcn_mfma_f32_16x16x32_bf16(a, b, c, 0, 0, 0);
}

static __device__ __forceinline__ void gload_lds16(const void* g, void* l) {
  __builtin_amdgcn_global_load_lds(
      (const __attribute__((address_space(1))) unsigned int*)g,
      (__attribute__((address_space(3))) unsigned int*)l, 16, 0, 0);
}

// ---------------- f32 -> bf16 convert (vectorized) ----------------
__global__ __launch_bounds__(256) void k_cvt(const float* __restrict__ in,
                                             __bf16* __restrict__ out, int n4) {
  for (int i = blockIdx.x * blockDim.x + threadIdx.x; i < n4;
       i += gridDim.x * blockDim.x) {
    float4 v = reinterpret_cast<const float4*>(in)[i];
    bf16x4 o = {(__bf16)v.x, (__bf16)v.y, (__bf16)v.z, (__bf16)v.w};
    reinterpret_cast<bf16x4*>(out)[i] = o;
  }
}

// ---------------- weight convert + transpose: Wt[n][k] = W[k][n] ----------------
__global__ __launch_bounds__(256) void k_wt(const float* __restrict__ W,
                                            __bf16* __restrict__ Wt) {
  __shared__ float tile[64][65];
  int bx = blockIdx.x;
  int by = blockIdx.y;
  int tid = threadIdx.x;
#pragma unroll
  for (int p = 0; p < 16; p++) {
    int idx = p * 256 + tid;
    int r = idx >> 6, c = idx & 63;
    tile[r][c] = W[(size_t)(by * 64 + r) * 512 + bx * 64 + c];
  }
  __syncthreads();
#pragma unroll
  for (int p = 0; p < 16; p++) {
    int idx = p * 256 + tid;
    int rn = idx >> 6, ck = idx & 63;
    Wt[(size_t)(bx * 64 + rn) * 512 + by * 64 + ck] = (__bf16)tile[ck][rn];
  }
}

// ---------------- GEMM: C[M,512] = A[M,512](bf16) @ W (via Wt[n][k] bf16) ----------------
template <int OUT_MODE>
__global__ __launch_bounds__(256) void k_gemm(const __bf16* __restrict__ A,
                                              const __bf16* __restrict__ Bt,
                                              void* __restrict__ Cout,
                                              float scale) {
  constexpr bool SWAP = (OUT_MODE != 2);
  __shared__ __bf16 As[128][72];
  __shared__ __bf16 Bs[64][72];
  const int tid = threadIdx.x;
  const int wid = tid >> 6, lane = tid & 63;
  const int g = lane >> 4, c = lane & 15;
  const int m0 = blockIdx.x * 128, n0 = blockIdx.y * 64;
  const int wr = wid >> 1, wc = wid & 1;

  f32x4 acc[4][2];
#pragma unroll
  for (int i = 0; i < 4; i++)
#pragma unroll
    for (int j = 0; j < 2; j++) acc[i][j] = (f32x4){0.f, 0.f, 0.f, 0.f};

  for (int k0 = 0; k0 < 512; k0 += 64) {
#pragma unroll
    for (int q = 0; q < 4; q++) {
      int idx = (q * 256 + tid) * 8;
      int r = idx >> 6, cc = idx & 63;
      bf16x8 v = *reinterpret_cast<const bf16x8*>(A + (size_t)(m0 + r) * 512 + k0 + cc);
      *reinterpret_cast<bf16x8*>(&As[r][cc]) = v;
    }
#pragma unroll
    for (int q = 0; q < 2; q++) {
      int idx = (q * 256 + tid) * 8;
      int r = idx >> 6, cc = idx & 63;
      bf16x8 v = *reinterpret_cast<const bf16x8*>(Bt + (size_t)(n0 + r) * 512 + k0 + cc);
      *reinterpret_cast<bf16x8*>(&Bs[r][cc]) = v;
    }
    __syncthreads();
#pragma unroll
    for (int kk = 0; kk < 2; kk++) {
      bf16x8 bfrag[2];
#pragma unroll
      for (int nf = 0; nf < 2; nf++)
        bfrag[nf] = *reinterpret_cast<const bf16x8*>(&Bs[wc * 32 + nf * 16 + c][kk * 32 + g * 8]);
#pragma unroll
      for (int mf = 0; mf < 4; mf++) {
        bf16x8 afrag = *reinterpret_cast<const bf16x8*>(&As[wr * 64 + mf * 16 + c][kk * 32 + g * 8]);
#pragma unroll
        for (int nf = 0; nf < 2; nf++)
          acc[mf][nf] = SWAP ? mfma16(bfrag[nf], afrag, acc[mf][nf])
                             : mfma16(afrag, bfrag[nf], acc[mf][nf]);
      }
    }
    __syncthreads();
  }
#pragma unroll
  for (int mf = 0; mf < 4; mf++)
#pragma unroll
    for (int nf = 0; nf < 2; nf++) {
      if (OUT_MODE == 0) {
        int mm = m0 + wr * 64 + mf * 16 + c;
        int nnb = n0 + wc * 32 + nf * 16 + g * 4;
        int b = mm >> 12, s = mm & 4095, h = nnb >> 6, d = nnb & 63;
        bf16x4 ov = {(__bf16)(acc[mf][nf][0] * scale), (__bf16)(acc[mf][nf][1] * scale),
                     (__bf16)(acc[mf][nf][2] * scale), (__bf16)(acc[mf][nf][3] * scale)};
        *reinterpret_cast<bf16x4*>((__bf16*)Cout + ((((size_t)b * 8 + h) * 4096) + s) * 64 + d) = ov;
      } else if (OUT_MODE == 1) {
        int mm = m0 + wr * 64 + mf * 16 + c;
        int nnb = n0 + wc * 32 + nf * 16 + g * 4;
        f32x4 ov = acc[mf][nf] * scale;
        *reinterpret_cast<f32x4*>((float*)Cout + (size_t)mm * 512 + nnb) = ov;
      } else {
        int mmb = m0 + wr * 64 + mf * 16 + g * 4;
        int nn = n0 + wc * 32 + nf * 16 + c;
        int b = mmb >> 12, s = mmb & 4095, h = nn >> 6, d = nn & 63;
        bf16x4 ov = {(__bf16)(acc[mf][nf][0] * scale), (__bf16)(acc[mf][nf][1] * scale),
                     (__bf16)(acc[mf][nf][2] * scale), (__bf16)(acc[mf][nf][3] * scale)};
        *reinterpret_cast<bf16x4*>((__bf16*)Cout + (((size_t)b * 8 + h) * 64 + d) * 4096 + s) = ov;
      }
    }
}

// ---------------- flash attention partial: key-split halves, fixed-max softmax ----------------
// grid dim3(32,16,2): x=qb (128 q/block), y=bh, z=kh (key half). 4 waves, 32 q/wave
// (2 subtiles sharing K-frag reads). 32 chunks of 64 keys per block.
// LDS: KVs 32KB + single P 8KB (PV serialized per subtile) = 40KB -> 4 blocks/CU, 4 waves/SIMD.
// Outputs UNNORMALIZED O (bf16) + l (f32); fixed max makes combine = add.
__global__ __launch_bounds__(256, 4) void k_attn(const __bf16* __restrict__ Q,
                                                 const __bf16* __restrict__ K,
                                                 const __bf16* __restrict__ Vt,
                                                 const float* __restrict__ bias,
                                                 __bf16* __restrict__ Opart,
                                                 float* __restrict__ lpart) {
  __shared__ __bf16 KVs[2][2][64][64];  // [dbuf][K/V][row][64], XOR-swizzled (^(row&7)<<4)
  __shared__ __bf16 Pl[4][16][64];      // per-wave P (one subtile at a time), same swizzle

  const int qb = blockIdx.x, bh = blockIdx.y, kh = blockIdx.z;
  const int kb0 = kh * 32;  // this half's first chunk
  const int tid = threadIdx.x, wid = tid >> 6, lane = tid & 63;
  const int g = lane >> 4, c = lane & 15;
  const int swz = (c & 7) << 4;
  const char* Kb = (const char*)(K + (size_t)bh * 4096 * 64);
  const char* Vb = (const char*)(Vt + (size_t)bh * 64 * 4096);
  const __bf16* Qh = Q + (size_t)bh * 4096 * 64;
  const int q0 = qb * 128 + wid * 32;
  const int myq0 = q0 + c, myq1 = q0 + 16 + c;

  auto stage = [&](int db, int chunk) {  // chunk is GLOBAL chunk index (0..63)
    const int reg = wid >> 1;
    char* dst0 = (char*)&KVs[db][reg][0][0] + (wid & 1) * 4096;
#pragma unroll
    for (int j = 0; j < 4; j++) {
      int Lp = (wid & 1) * 4096 + j * 1024 + lane * 16;
      int L = Lp ^ (((Lp >> 7) & 7) << 4);
      const char* src = (reg == 0)
          ? Kb + (size_t)chunk * 8192 + L
          : Vb + (size_t)(L >> 7) * 8192 + (size_t)chunk * 128 + (L & 127);
      gload_lds16(src, dst0 + j * 1024);
    }
  };

  const float* brow0 = bias + (size_t)myq0 * 4096;
  const float* brow1 = bias + (size_t)myq1 * 4096;

#define LOADB(dst, chunk)                                                      \
  {                                                                            \
    _Pragma("unroll") for (int f = 0; f < 4; f++) dst[0][f] =                  \
        *reinterpret_cast<const f32x4*>(brow0 + (chunk) * 64 + f * 16 + g * 4);\
    _Pragma("unroll") for (int f = 0; f < 4; f++) dst[1][f] =                  \
        *reinterpret_cast<const f32x4*>(brow1 + (chunk) * 64 + f * 16 + g * 4);\
  }

  bf16x8 qa[2][2];
  qa[0][0] = *reinterpret_cast<const bf16x8*>(Qh + (size_t)myq0 * 64 + g * 8);
  qa[0][1] = *reinterpret_cast<const bf16x8*>(Qh + (size_t)myq0 * 64 + 32 + g * 8);
  qa[1][0] = *reinterpret_cast<const bf16x8*>(Qh + (size_t)myq1 * 64 + g * 8);
  qa[1][1] = *reinterpret_cast<const bf16x8*>(Qh + (size_t)myq1 * 64 + 32 + g * 8);

  f32x4 lacc[2];
  lacc[0] = (f32x4){0.f, 0.f, 0.f, 0.f};
  lacc[1] = (f32x4){0.f, 0.f, 0.f, 0.f};
  f32x4 o[2][4];
#pragma unroll
  for (int qt = 0; qt < 2; qt++)
#pragma unroll
    for (int f = 0; f < 4; f++) o[qt][f] = (f32x4){0.f, 0.f, 0.f, 0.f};

  f32x4 bA[2][4], bB[2][4];
  const float NM = -FIXED_M * LOG2E;

  auto process = [&](int db, f32x4 (&bv)[2][4]) {
    // this chunk's stage+bias drained; next stage(4)+bias(8) stay in flight
    asm volatile("s_waitcnt vmcnt(12)" ::: "memory");
    __builtin_amdgcn_s_barrier();
    const char* Kl = (const char*)&KVs[db][0][0][0];
    const char* Vl = (const char*)&KVs[db][1][0][0];
    f32x4 st[2][4];
    __builtin_amdgcn_s_setprio(1);
#pragma unroll
    for (int f = 0; f < 4; f++) {
      const char* rb = Kl + (f * 16 + c) * 128;
      bf16x8 k0 = *reinterpret_cast<const bf16x8*>(rb + ((g * 16) ^ swz));
      bf16x8 k1 = *reinterpret_cast<const bf16x8*>(rb + ((64 + g * 16) ^ swz));
      st[0][f] = mfma16(k1, qa[0][1], mfma16(k0, qa[0][0], bv[0][f]));
      st[1][f] = mfma16(k1, qa[1][1], mfma16(k0, qa[1][0], bv[1][f]));
    }
    __builtin_amdgcn_s_setprio(0);
    // per subtile: softmax -> P LDS (single buffer, serialized) -> PV
    char* Pw = (char*)&Pl[wid][0][0] + c * 128;
#pragma unroll
    for (int qt = 0; qt < 2; qt++) {
#pragma unroll
      for (int f = 0; f < 4; f++) {
#pragma unroll
        for (int r = 0; r < 4; r++)
          st[qt][f][r] = __builtin_exp2f(__builtin_fmaf(st[qt][f][r], LOG2E, NM));
        lacc[qt] += st[qt][f];
        bf16x4 pk = {(__bf16)st[qt][f][0], (__bf16)st[qt][f][1],
                     (__bf16)st[qt][f][2], (__bf16)st[qt][f][3]};
        *reinterpret_cast<bf16x4*>(Pw + ((f * 32 + g * 8) ^ swz)) = pk;
      }
      __builtin_amdgcn_s_setprio(1);
#pragma unroll
      for (int kk = 0; kk < 2; kk++) {
        bf16x8 pb = *reinterpret_cast<const bf16x8*>(Pw + ((kk * 64 + g * 16) ^ swz));
#pragma unroll
        for (int fd = 0; fd < 4; fd++) {
          const char* rb = Vl + (fd * 16 + c) * 128;
          bf16x8 va = *reinterpret_cast<const bf16x8*>(rb + ((kk * 64 + g * 16) ^ swz));
          o[qt][fd] = mfma16(va, pb, o[qt][fd]);
        }
      }
      __builtin_amdgcn_s_setprio(0);
    }
    __builtin_amdgcn_s_barrier();  // all waves done reading KVs[db]
  };

  // prologue (chunks are global indices kb0+local)
  stage(0, kb0 + 0);
  asm volatile("" ::: "memory");
  stage(1, kb0 + 1);
  asm volatile("" ::: "memory");
  LOADB(bA, kb0 + 0);
  asm volatile("" ::: "memory");
  LOADB(bB, kb0 + 1);
  asm volatile("" ::: "memory");

  for (int t = 0; t < 32; t += 2) {
    process(0, bA);
    stage(0, kb0 + ((t + 2) & 31));
    asm volatile("" ::: "memory");
    LOADB(bA, kb0 + ((t + 2) & 31));
    asm volatile("" ::: "memory");
    process(1, bB);
    stage(1, kb0 + ((t + 3) & 31));
    asm volatile("" ::: "memory");
    LOADB(bB, kb0 + ((t + 3) & 31));
    asm volatile("" ::: "memory");
  }

  // epilogue: store UNNORMALIZED partial O (bf16) + l (f32)
#pragma unroll
  for (int qt = 0; qt < 2; qt++) {
    float l = lacc[qt][0] + lacc[qt][1] + lacc[qt][2] + lacc[qt][3];
    l += __shfl_xor(l, 16);
    l += __shfl_xor(l, 32);
    int myq = (qt == 0) ? myq0 : myq1;
    __bf16* Oprow = Opart + (((size_t)kh * 16 + bh) * 4096 + myq) * 64;
#pragma unroll
    for (int fd = 0; fd < 4; fd++) {
      bf16x4 ov = {(__bf16)o[qt][fd][0], (__bf16)o[qt][fd][1],
                   (__bf16)o[qt][fd][2], (__bf16)o[qt][fd][3]};
      *reinterpret_cast<bf16x4*>(Oprow + fd * 16 + g * 4) = ov;
    }
    if (g == 0) lpart[((size_t)kh * 16 + bh) * 4096 + myq] = l;
  }
#undef LOADB
}

// ---------------- combine halves: O = (Oa+Ob)/(la+lb), write [B,S,512] bf16 ----------------
__global__ __launch_bounds__(256) void k_red(const __bf16* __restrict__ Op,
                                             const float* __restrict__ lp,
                                             __bf16* __restrict__ AO) {
  int i = blockIdx.x * 256 + threadIdx.x;  // [0, 16*4096*16)
  int bh = i >> 16;
  int rem = i & 65535;
  int s = rem >> 4;
  int d4 = (rem & 15) << 2;
  int b = bh >> 3, h = bh & 7;
  size_t base0 = ((size_t)bh * 4096 + s) * 64 + d4;
  size_t base1 = ((size_t)(16 + bh) * 4096 + s) * 64 + d4;
  bf16x4 a = *reinterpret_cast<const bf16x4*>(Op + base0);
  bf16x4 cc = *reinterpret_cast<const bf16x4*>(Op + base1);
  float la = lp[(size_t)bh * 4096 + s];
  float lb = lp[(size_t)(16 + bh) * 4096 + s];
  float inv = 1.f / (la + lb);
  bf16x4 ov = {(__bf16)(((float)a[0] + (float)cc[0]) * inv),
               (__bf16)(((float)a[1] + (float)cc[1]) * inv),
               (__bf16)(((float)a[2] + (float)cc[2]) * inv),
               (__bf16)(((float)a[3] + (float)cc[3]) * inv)};
  *reinterpret_cast<bf16x4*>(AO + ((size_t)b * 4096 + s) * 512 + h * 64 + d4) = ov;
}

// ---------------- launch ----------------
extern "C" void kernel_launch(void* const* d_in, const int* in_sizes, int n_in,
                              void* d_out, int out_size, void* d_ws, size_t ws_size,
                              hipStream_t stream) {
  const float* xq = (const float*)d_in[0];
  const float* xm = (const float*)d_in[1];
  const float* bias = (const float*)d_in[2];
  const float* Wq = (const float*)d_in[3];
  const float* Wk = (const float*)d_in[4];
  const float* Wv = (const float*)d_in[5];
  const float* Wo = (const float*)d_in[6];

  const size_t MB = 1024 * 1024;
  char* ws = (char*)d_ws;
  // Overlay plan (stream-ordered, all safe):
  //   [0,16)   xq_b, xm_b  -> later Opart (attn writes after both are dead)
  //   [16,16.5) wqt        -> later lpart (attn writes after gemm Q consumed wqt)
  __bf16* xq_b = (__bf16*)(ws + 0);
  __bf16* xm_b = (__bf16*)(ws + 8 * MB);
  __bf16* Opart = (__bf16*)(ws + 0);            // 16 MB [kh][bh][s][64]
  __bf16* wqt = (__bf16*)(ws + 16 * MB);
  float* lpart = (float*)(ws + 16 * MB);        // 512 KB [kh][bh][s]
  __bf16* wkt = (__bf16*)(ws + 16 * MB + 524288);
  __bf16* wvt = (__bf16*)(ws + 17 * MB);
  __bf16* wot = (__bf16*)(ws + 17 * MB + 524288);
  __bf16* Qb = (__bf16*)(ws + 18 * MB);
  __bf16* Kb = (__bf16*)(ws + 26 * MB);
  __bf16* AOb = (__bf16*)(ws + 34 * MB);
  __bf16* Vtb = (__bf16*)(ws + 42 * MB);
  if (ws_size < 50 * MB) return;

  const int n4 = 8192 * 512 / 4;
  k_cvt<<<2048, 256, 0, stream>>>(xq, xq_b, n4);
  k_cvt<<<2048, 256, 0, stream>>>(xm, xm_b, n4);
  k_wt<<<dim3(8, 8), 256, 0, stream>>>(Wq, wqt);
  k_wt<<<dim3(8, 8), 256, 0, stream>>>(Wk, wkt);
  k_wt<<<dim3(8, 8), 256, 0, stream>>>(Wv, wvt);
  k_wt<<<dim3(8, 8), 256, 0, stream>>>(Wo, wot);

  k_gemm<0><<<dim3(64, 8), 256, 0, stream>>>(xq_b, wqt, Qb, 0.125f);
  k_gemm<0><<<dim3(64, 8), 256, 0, stream>>>(xm_b, wkt, Kb, 1.0f);
  k_gemm<2><<<dim3(64, 8), 256, 0, stream>>>(xm_b, wvt, Vtb, 1.0f);

  k_attn<<<dim3(32, 16, 2), 256, 0, stream>>>(Qb, Kb, Vtb, bias, Opart, lpart);
  k_red<<<4096, 256, 0, stream>>>(Opart, lpart, AOb);

  k_gemm<1><<<dim3(64, 8), 256, 0, stream>>>(AOb, wot, d_out, 1.0f);
}

// Round 9
// 254.432 us; speedup vs baseline: 2.1105x; 2.1105x over previous
//
#include <hip/hip_runtime.h>
#include <hip/hip_bf16.h>

typedef __attribute__((ext_vector_type(8))) __bf16 bf16x8;
typedef __attribute__((ext_vector_type(4))) __bf16 bf16x4;
typedef __attribute__((ext_vector_type(4))) float f32x4;

#define LOG2E 1.4426950408889634f
#define FIXED_M 16.0f

static __device__ __forceinline__ f32x4 mfma16(bf16x8 a, bf16x8 b, f32x4 c) {
  return __builtin_amdgcn_mfma_f32_16x16x32_bf16(a, b, c, 0, 0, 0);
}

static __device__ __forceinline__ void gload_lds16(const void* g, void* l) {
  __builtin_amdgcn_global_load_lds(
      (const __attribute__((address_space(1))) unsigned int*)g,
      (__attribute__((address_space(3))) unsigned int*)l, 16, 0, 0);
}

// ---------------- f32 -> bf16 convert (vectorized) ----------------
__global__ __launch_bounds__(256) void k_cvt(const float* __restrict__ in,
                                             __bf16* __restrict__ out, int n4) {
  for (int i = blockIdx.x * blockDim.x + threadIdx.x; i < n4;
       i += gridDim.x * blockDim.x) {
    float4 v = reinterpret_cast<const float4*>(in)[i];
    bf16x4 o = {(__bf16)v.x, (__bf16)v.y, (__bf16)v.z, (__bf16)v.w};
    reinterpret_cast<bf16x4*>(out)[i] = o;
  }
}

// ---------------- weight convert + transpose: Wt[n][k] = W[k][n] ----------------
__global__ __launch_bounds__(256) void k_wt(const float* __restrict__ W,
                                            __bf16* __restrict__ Wt) {
  __shared__ float tile[64][65];
  int bx = blockIdx.x;
  int by = blockIdx.y;
  int tid = threadIdx.x;
#pragma unroll
  for (int p = 0; p < 16; p++) {
    int idx = p * 256 + tid;
    int r = idx >> 6, c = idx & 63;
    tile[r][c] = W[(size_t)(by * 64 + r) * 512 + bx * 64 + c];
  }
  __syncthreads();
#pragma unroll
  for (int p = 0; p < 16; p++) {
    int idx = p * 256 + tid;
    int rn = idx >> 6, ck = idx & 63;
    Wt[(size_t)(bx * 64 + rn) * 512 + by * 64 + ck] = (__bf16)tile[ck][rn];
  }
}

// ---------------- GEMM: C[M,512] = A[M,512](bf16) @ W (via Wt[n][k] bf16) ----------------
template <int OUT_MODE>
__global__ __launch_bounds__(256) void k_gemm(const __bf16* __restrict__ A,
                                              const __bf16* __restrict__ Bt,
                                              void* __restrict__ Cout,
                                              float scale) {
  constexpr bool SWAP = (OUT_MODE != 2);
  __shared__ __bf16 As[128][72];
  __shared__ __bf16 Bs[64][72];
  const int tid = threadIdx.x;
  const int wid = tid >> 6, lane = tid & 63;
  const int g = lane >> 4, c = lane & 15;
  const int m0 = blockIdx.x * 128, n0 = blockIdx.y * 64;
  const int wr = wid >> 1, wc = wid & 1;

  f32x4 acc[4][2];
#pragma unroll
  for (int i = 0; i < 4; i++)
#pragma unroll
    for (int j = 0; j < 2; j++) acc[i][j] = (f32x4){0.f, 0.f, 0.f, 0.f};

  for (int k0 = 0; k0 < 512; k0 += 64) {
#pragma unroll
    for (int q = 0; q < 4; q++) {
      int idx = (q * 256 + tid) * 8;
      int r = idx >> 6, cc = idx & 63;
      bf16x8 v = *reinterpret_cast<const bf16x8*>(A + (size_t)(m0 + r) * 512 + k0 + cc);
      *reinterpret_cast<bf16x8*>(&As[r][cc]) = v;
    }
#pragma unroll
    for (int q = 0; q < 2; q++) {
      int idx = (q * 256 + tid) * 8;
      int r = idx >> 6, cc = idx & 63;
      bf16x8 v = *reinterpret_cast<const bf16x8*>(Bt + (size_t)(n0 + r) * 512 + k0 + cc);
      *reinterpret_cast<bf16x8*>(&Bs[r][cc]) = v;
    }
    __syncthreads();
#pragma unroll
    for (int kk = 0; kk < 2; kk++) {
      bf16x8 bfrag[2];
#pragma unroll
      for (int nf = 0; nf < 2; nf++)
        bfrag[nf] = *reinterpret_cast<const bf16x8*>(&Bs[wc * 32 + nf * 16 + c][kk * 32 + g * 8]);
#pragma unroll
      for (int mf = 0; mf < 4; mf++) {
        bf16x8 afrag = *reinterpret_cast<const bf16x8*>(&As[wr * 64 + mf * 16 + c][kk * 32 + g * 8]);
#pragma unroll
        for (int nf = 0; nf < 2; nf++)
          acc[mf][nf] = SWAP ? mfma16(bfrag[nf], afrag, acc[mf][nf])
                             : mfma16(afrag, bfrag[nf], acc[mf][nf]);
      }
    }
    __syncthreads();
  }
#pragma unroll
  for (int mf = 0; mf < 4; mf++)
#pragma unroll
    for (int nf = 0; nf < 2; nf++) {
      if (OUT_MODE == 0) {
        int mm = m0 + wr * 64 + mf * 16 + c;
        int nnb = n0 + wc * 32 + nf * 16 + g * 4;
        int b = mm >> 12, s = mm & 4095, h = nnb >> 6, d = nnb & 63;
        bf16x4 ov = {(__bf16)(acc[mf][nf][0] * scale), (__bf16)(acc[mf][nf][1] * scale),
                     (__bf16)(acc[mf][nf][2] * scale), (__bf16)(acc[mf][nf][3] * scale)};
        *reinterpret_cast<bf16x4*>((__bf16*)Cout + ((((size_t)b * 8 + h) * 4096) + s) * 64 + d) = ov;
      } else if (OUT_MODE == 1) {
        int mm = m0 + wr * 64 + mf * 16 + c;
        int nnb = n0 + wc * 32 + nf * 16 + g * 4;
        f32x4 ov = acc[mf][nf] * scale;
        *reinterpret_cast<f32x4*>((float*)Cout + (size_t)mm * 512 + nnb) = ov;
      } else {
        int mmb = m0 + wr * 64 + mf * 16 + g * 4;
        int nn = n0 + wc * 32 + nf * 16 + c;
        int b = mmb >> 12, s = mmb & 4095, h = nn >> 6, d = nn & 63;
        bf16x4 ov = {(__bf16)(acc[mf][nf][0] * scale), (__bf16)(acc[mf][nf][1] * scale),
                     (__bf16)(acc[mf][nf][2] * scale), (__bf16)(acc[mf][nf][3] * scale)};
        *reinterpret_cast<bf16x4*>((__bf16*)Cout + (((size_t)b * 8 + h) * 64 + d) * 4096 + s) = ov;
      }
    }
}

// ---------------- flash attention partial: key-split halves, fixed-max softmax ----------------
// grid dim3(32,16,2): x=qb (128 q/block), y=bh, z=kh (key half). 4 waves, 32 q/wave
// (2 subtiles sharing K-frag reads). 32 chunks of 64 keys per block.
// LDS: KVs 32KB + single P 8KB = 40KB -> LDS-limited 4 blocks/CU (no launch_bounds forcing:
// (256,4) made the allocator split to 64 arch-VGPRs and spill ~930MB/dispatch — r8 lesson).
// Outputs UNNORMALIZED O (bf16) + l (f32); fixed max makes combine = add.
__global__ __launch_bounds__(256, 2) void k_attn(const __bf16* __restrict__ Q,
                                                 const __bf16* __restrict__ K,
                                                 const __bf16* __restrict__ Vt,
                                                 const float* __restrict__ bias,
                                                 __bf16* __restrict__ Opart,
                                                 float* __restrict__ lpart) {
  __shared__ __bf16 KVs[2][2][64][64];  // [dbuf][K/V][row][64], XOR-swizzled (^(row&7)<<4)
  __shared__ __bf16 Pl[4][16][64];      // per-wave P (one subtile at a time), same swizzle

  const int qb = blockIdx.x, bh = blockIdx.y, kh = blockIdx.z;
  const int kb0 = kh * 32;  // this half's first chunk
  const int tid = threadIdx.x, wid = tid >> 6, lane = tid & 63;
  const int g = lane >> 4, c = lane & 15;
  const int swz = (c & 7) << 4;
  const char* Kb = (const char*)(K + (size_t)bh * 4096 * 64);
  const char* Vb = (const char*)(Vt + (size_t)bh * 64 * 4096);
  const __bf16* Qh = Q + (size_t)bh * 4096 * 64;
  const int q0 = qb * 128 + wid * 32;
  const int myq0 = q0 + c, myq1 = q0 + 16 + c;

  auto stage = [&](int db, int chunk) {  // chunk is GLOBAL chunk index (0..63)
    const int reg = wid >> 1;
    char* dst0 = (char*)&KVs[db][reg][0][0] + (wid & 1) * 4096;
#pragma unroll
    for (int j = 0; j < 4; j++) {
      int Lp = (wid & 1) * 4096 + j * 1024 + lane * 16;
      int L = Lp ^ (((Lp >> 7) & 7) << 4);
      const char* src = (reg == 0)
          ? Kb + (size_t)chunk * 8192 + L
          : Vb + (size_t)(L >> 7) * 8192 + (size_t)chunk * 128 + (L & 127);
      gload_lds16(src, dst0 + j * 1024);
    }
  };

  const float* brow0 = bias + (size_t)myq0 * 4096;
  const float* brow1 = bias + (size_t)myq1 * 4096;

#define LOADB(dst, chunk)                                                      \
  {                                                                            \
    _Pragma("unroll") for (int f = 0; f < 4; f++) dst[0][f] =                  \
        *reinterpret_cast<const f32x4*>(brow0 + (chunk) * 64 + f * 16 + g * 4);\
    _Pragma("unroll") for (int f = 0; f < 4; f++) dst[1][f] =                  \
        *reinterpret_cast<const f32x4*>(brow1 + (chunk) * 64 + f * 16 + g * 4);\
  }

  bf16x8 qa[2][2];
  qa[0][0] = *reinterpret_cast<const bf16x8*>(Qh + (size_t)myq0 * 64 + g * 8);
  qa[0][1] = *reinterpret_cast<const bf16x8*>(Qh + (size_t)myq0 * 64 + 32 + g * 8);
  qa[1][0] = *reinterpret_cast<const bf16x8*>(Qh + (size_t)myq1 * 64 + g * 8);
  qa[1][1] = *reinterpret_cast<const bf16x8*>(Qh + (size_t)myq1 * 64 + 32 + g * 8);

  f32x4 lacc[2];
  lacc[0] = (f32x4){0.f, 0.f, 0.f, 0.f};
  lacc[1] = (f32x4){0.f, 0.f, 0.f, 0.f};
  f32x4 o[2][4];
#pragma unroll
  for (int qt = 0; qt < 2; qt++)
#pragma unroll
    for (int f = 0; f < 4; f++) o[qt][f] = (f32x4){0.f, 0.f, 0.f, 0.f};

  f32x4 bA[2][4], bB[2][4];
  const float NM = -FIXED_M * LOG2E;

  auto process = [&](int db, f32x4 (&bv)[2][4]) {
    // this chunk's stage+bias drained; next stage(4)+bias(8) stay in flight
    asm volatile("s_waitcnt vmcnt(12)" ::: "memory");
    __builtin_amdgcn_s_barrier();
    const char* Kl = (const char*)&KVs[db][0][0][0];
    const char* Vl = (const char*)&KVs[db][1][0][0];
    f32x4 st[2][4];
    __builtin_amdgcn_s_setprio(1);
#pragma unroll
    for (int f = 0; f < 4; f++) {
      const char* rb = Kl + (f * 16 + c) * 128;
      bf16x8 k0 = *reinterpret_cast<const bf16x8*>(rb + ((g * 16) ^ swz));
      bf16x8 k1 = *reinterpret_cast<const bf16x8*>(rb + ((64 + g * 16) ^ swz));
      st[0][f] = mfma16(k1, qa[0][1], mfma16(k0, qa[0][0], bv[0][f]));
      st[1][f] = mfma16(k1, qa[1][1], mfma16(k0, qa[1][0], bv[1][f]));
    }
    __builtin_amdgcn_s_setprio(0);
    // per subtile: softmax -> P LDS (single buffer, serialized) -> PV
    char* Pw = (char*)&Pl[wid][0][0] + c * 128;
#pragma unroll
    for (int qt = 0; qt < 2; qt++) {
#pragma unroll
      for (int f = 0; f < 4; f++) {
#pragma unroll
        for (int r = 0; r < 4; r++)
          st[qt][f][r] = __builtin_exp2f(__builtin_fmaf(st[qt][f][r], LOG2E, NM));
        lacc[qt] += st[qt][f];
        bf16x4 pk = {(__bf16)st[qt][f][0], (__bf16)st[qt][f][1],
                     (__bf16)st[qt][f][2], (__bf16)st[qt][f][3]};
        *reinterpret_cast<bf16x4*>(Pw + ((f * 32 + g * 8) ^ swz)) = pk;
      }
      __builtin_amdgcn_s_setprio(1);
#pragma unroll
      for (int kk = 0; kk < 2; kk++) {
        bf16x8 pb = *reinterpret_cast<const bf16x8*>(Pw + ((kk * 64 + g * 16) ^ swz));
#pragma unroll
        for (int fd = 0; fd < 4; fd++) {
          const char* rb = Vl + (fd * 16 + c) * 128;
          bf16x8 va = *reinterpret_cast<const bf16x8*>(rb + ((kk * 64 + g * 16) ^ swz));
          o[qt][fd] = mfma16(va, pb, o[qt][fd]);
        }
      }
      __builtin_amdgcn_s_setprio(0);
    }
    __builtin_amdgcn_s_barrier();  // all waves done reading KVs[db]
  };

  // prologue (chunks are global indices kb0+local)
  stage(0, kb0 + 0);
  asm volatile("" ::: "memory");
  stage(1, kb0 + 1);
  asm volatile("" ::: "memory");
  LOADB(bA, kb0 + 0);
  asm volatile("" ::: "memory");
  LOADB(bB, kb0 + 1);
  asm volatile("" ::: "memory");

  for (int t = 0; t < 32; t += 2) {
    process(0, bA);
    stage(0, kb0 + ((t + 2) & 31));
    asm volatile("" ::: "memory");
    LOADB(bA, kb0 + ((t + 2) & 31));
    asm volatile("" ::: "memory");
    process(1, bB);
    stage(1, kb0 + ((t + 3) & 31));
    asm volatile("" ::: "memory");
    LOADB(bB, kb0 + ((t + 3) & 31));
    asm volatile("" ::: "memory");
  }

  // epilogue: store UNNORMALIZED partial O (bf16) + l (f32)
#pragma unroll
  for (int qt = 0; qt < 2; qt++) {
    float l = lacc[qt][0] + lacc[qt][1] + lacc[qt][2] + lacc[qt][3];
    l += __shfl_xor(l, 16);
    l += __shfl_xor(l, 32);
    int myq = (qt == 0) ? myq0 : myq1;
    __bf16* Oprow = Opart + (((size_t)kh * 16 + bh) * 4096 + myq) * 64;
#pragma unroll
    for (int fd = 0; fd < 4; fd++) {
      bf16x4 ov = {(__bf16)o[qt][fd][0], (__bf16)o[qt][fd][1],
                   (__bf16)o[qt][fd][2], (__bf16)o[qt][fd][3]};
      *reinterpret_cast<bf16x4*>(Oprow + fd * 16 + g * 4) = ov;
    }
    if (g == 0) lpart[((size_t)kh * 16 + bh) * 4096 + myq] = l;
  }
#undef LOADB
}

// ---------------- combine halves: O = (Oa+Ob)/(la+lb), write [B,S,512] bf16 ----------------
__global__ __launch_bounds__(256) void k_red(const __bf16* __restrict__ Op,
                                             const float* __restrict__ lp,
                                             __bf16* __restrict__ AO) {
  int i = blockIdx.x * 256 + threadIdx.x;  // [0, 16*4096*16)
  int bh = i >> 16;
  int rem = i & 65535;
  int s = rem >> 4;
  int d4 = (rem & 15) << 2;
  int b = bh >> 3, h = bh & 7;
  size_t base0 = ((size_t)bh * 4096 + s) * 64 + d4;
  size_t base1 = ((size_t)(16 + bh) * 4096 + s) * 64 + d4;
  bf16x4 a = *reinterpret_cast<const bf16x4*>(Op + base0);
  bf16x4 cc = *reinterpret_cast<const bf16x4*>(Op + base1);
  float la = lp[(size_t)bh * 4096 + s];
  float lb = lp[(size_t)(16 + bh) * 4096 + s];
  float inv = 1.f / (la + lb);
  bf16x4 ov = {(__bf16)(((float)a[0] + (float)cc[0]) * inv),
               (__bf16)(((float)a[1] + (float)cc[1]) * inv),
               (__bf16)(((float)a[2] + (float)cc[2]) * inv),
               (__bf16)(((float)a[3] + (float)cc[3]) * inv)};
  *reinterpret_cast<bf16x4*>(AO + ((size_t)b * 4096 + s) * 512 + h * 64 + d4) = ov;
}

// ---------------- launch ----------------
extern "C" void kernel_launch(void* const* d_in, const int* in_sizes, int n_in,
                              void* d_out, int out_size, void* d_ws, size_t ws_size,
                              hipStream_t stream) {
  const float* xq = (const float*)d_in[0];
  const float* xm = (const float*)d_in[1];
  const float* bias = (const float*)d_in[2];
  const float* Wq = (const float*)d_in[3];
  const float* Wk = (const float*)d_in[4];
  const float* Wv = (const float*)d_in[5];
  const float* Wo = (const float*)d_in[6];

  const size_t MB = 1024 * 1024;
  char* ws = (char*)d_ws;
  // Overlay plan (stream-ordered, all safe):
  //   [0,16)   xq_b, xm_b  -> later Opart (attn writes after both are dead)
  //   [16,16.5) wqt        -> later lpart (attn writes after gemm Q consumed wqt)
  __bf16* xq_b = (__bf16*)(ws + 0);
  __bf16* xm_b = (__bf16*)(ws + 8 * MB);
  __bf16* Opart = (__bf16*)(ws + 0);            // 16 MB [kh][bh][s][64]
  __bf16* wqt = (__bf16*)(ws + 16 * MB);
  float* lpart = (float*)(ws + 16 * MB);        // 512 KB [kh][bh][s]
  __bf16* wkt = (__bf16*)(ws + 16 * MB + 524288);
  __bf16* wvt = (__bf16*)(ws + 17 * MB);
  __bf16* wot = (__bf16*)(ws + 17 * MB + 524288);
  __bf16* Qb = (__bf16*)(ws + 18 * MB);
  __bf16* Kb = (__bf16*)(ws + 26 * MB);
  __bf16* AOb = (__bf16*)(ws + 34 * MB);
  __bf16* Vtb = (__bf16*)(ws + 42 * MB);
  if (ws_size < 50 * MB) return;

  const int n4 = 8192 * 512 / 4;
  k_cvt<<<2048, 256, 0, stream>>>(xq, xq_b, n4);
  k_cvt<<<2048, 256, 0, stream>>>(xm, xm_b, n4);
  k_wt<<<dim3(8, 8), 256, 0, stream>>>(Wq, wqt);
  k_wt<<<dim3(8, 8), 256, 0, stream>>>(Wk, wkt);
  k_wt<<<dim3(8, 8), 256, 0, stream>>>(Wv, wvt);
  k_wt<<<dim3(8, 8), 256, 0, stream>>>(Wo, wot);

  k_gemm<0><<<dim3(64, 8), 256, 0, stream>>>(xq_b, wqt, Qb, 0.125f);
  k_gemm<0><<<dim3(64, 8), 256, 0, stream>>>(xm_b, wkt, Kb, 1.0f);
  k_gemm<2><<<dim3(64, 8), 256, 0, stream>>>(xm_b, wvt, Vtb, 1.0f);

  k_attn<<<dim3(32, 16, 2), 256, 0, stream>>>(Qb, Kb, Vtb, bias, Opart, lpart);
  k_red<<<4096, 256, 0, stream>>>(Opart, lpart, AOb);

  k_gemm<1><<<dim3(64, 8), 256, 0, stream>>>(AOb, wot, d_out, 1.0f);
}